// Round 4
// baseline (318.275 us; speedup 1.0000x reference)
//
#include <hip/hip_runtime.h>

#define Bn   32
#define HIN  56
#define WIN  56
#define Cc   256
#define HG   28
#define WG   28
#define NPIX (HG*WG)                    // 784

#define GIN_SIZE (Bn*HIN*WIN*Cc)        // 25690112
#define GW_SIZE  (9*Cc*Cc)              // 589824
#define GW_OFF   GIN_SIZE
#define BIAS_OFF (GW_OFF + GW_SIZE)

typedef short bf16x8 __attribute__((ext_vector_type(8)));
typedef float f32x4  __attribute__((ext_vector_type(4)));

// native bf16 convert (RNE) — compiler fuses pairs into v_cvt_pk_bf16_f32
__device__ __forceinline__ unsigned short f2bf(float f) {
    return __builtin_bit_cast(unsigned short, (__bf16)f);
}

// [row][32] bf16 tile, 16B-granule XOR swizzle (k_grad_in, proven R1)
__device__ __forceinline__ int swz(int row, int k) {
    int g2 = (k >> 3) ^ (row & 3) ^ ((row >> 2) & 3);
    return row * 32 + (g2 << 3) + (k & 7);
}

// [row][64] bf16 tile, 16B-granule XOR swizzle (k_grad_wt, proven R2)
__device__ __forceinline__ int swz64(int row, int k) {
    int gq = ((k >> 3) ^ (row & 7) ^ ((row >> 4) & 7)) & 7;
    return row * 64 + (gq << 3) + (k & 7);
}

__global__ __launch_bounds__(256) void k_zero(float* __restrict__ p, int n) {
    int i = blockIdx.x * 256 + threadIdx.x;
    if (i < n) p[i] = 0.f;
}

// ---------------------------------------------------------------------------
// grad_in: per parity class, D[pix][ci] = sum_{tap,co} G_shift[pix][co]*W[ci][co]
// ---------------------------------------------------------------------------
__global__ __launch_bounds__(256) void k_grad_in(
    const float* __restrict__ g,      // [32,28,28,256]
    const float* __restrict__ wt,     // [3,3,256,256]
    float* __restrict__ out)          // [32,56,56,256]
{
    __shared__ unsigned short ga[128 * 32];   // [pix_local][k=co32]
    __shared__ unsigned short wb[128 * 32];   // [ci_local][k=co32]

    const int t    = threadIdx.x;
    const int l    = t & 63;
    const int wave = t >> 6;
    const int mbase = (wave & 1) * 64;
    const int nbase = (wave >> 1) * 64;
    const int q    = l >> 4;
    const int r16  = l & 15;

    const int mtile = blockIdx.x;
    const int ntile = blockIdx.y;
    const int cls   = blockIdx.z;
    const int dy = cls >> 1, dx = cls & 1;

    const int sp = t >> 1;
    const int sc = (t & 1) * 16;
    const int P_s   = mtile * 128 + sp;
    const int b_s   = P_s / NPIX;
    const int rem_s = P_s % NPIX;
    const int iy_s  = rem_s / WG;
    const int jx_s  = rem_s % WG;
    const int sci   = ntile * 128 + sp;

    f32x4 acc[4][4];
    #pragma unroll
    for (int a = 0; a < 4; ++a)
        #pragma unroll
        for (int b = 0; b < 4; ++b) acc[a][b] = (f32x4){0.f, 0.f, 0.f, 0.f};

    int aoff[4], boff[4];
    #pragma unroll
    for (int mf = 0; mf < 4; ++mf) aoff[mf] = swz(mbase + mf * 16 + r16, q * 8);
    #pragma unroll
    for (int nf = 0; nf < 4; ++nf) boff[nf] = swz(nbase + nf * 16 + r16, q * 8);

    const int nky = dy ? 1 : 2;
    const int nkx = dx ? 1 : 2;

    for (int ty = 0; ty < nky; ++ty) {
        const int di   = dy ? 0 : (ty == 0 ? -1 : 0);
        const int krow = dy ? 1 : (ty == 0 ?  2 : 0);
        for (int tx = 0; tx < nkx; ++tx) {
            const int dj   = dx ? 0 : (tx == 0 ? -1 : 0);
            const int kcol = dx ? 1 : (tx == 0 ?  2 : 0);

            const int gi = iy_s + di, gj = jx_s + dj;
            const bool valid = (gi >= 0) && (gj >= 0);
            const float* __restrict__ gsrc = g + (size_t)((b_s * HG + gi) * WG + gj) * Cc + sc;
            const float* __restrict__ wsrc = wt + (size_t)((krow * 3 + kcol) * Cc + sci) * Cc + sc;

            #pragma unroll 1
            for (int co0 = 0; co0 < Cc; co0 += 32) {
                __syncthreads();
                {
                    float4 v0 = make_float4(0,0,0,0), v1 = v0, v2 = v0, v3 = v0;
                    if (valid) {
                        v0 = *(const float4*)(gsrc + co0 + 0);
                        v1 = *(const float4*)(gsrc + co0 + 4);
                        v2 = *(const float4*)(gsrc + co0 + 8);
                        v3 = *(const float4*)(gsrc + co0 + 12);
                    }
                    ushort4 u0 = {f2bf(v0.x), f2bf(v0.y), f2bf(v0.z), f2bf(v0.w)};
                    ushort4 u1 = {f2bf(v1.x), f2bf(v1.y), f2bf(v1.z), f2bf(v1.w)};
                    ushort4 u2 = {f2bf(v2.x), f2bf(v2.y), f2bf(v2.z), f2bf(v2.w)};
                    ushort4 u3 = {f2bf(v3.x), f2bf(v3.y), f2bf(v3.z), f2bf(v3.w)};
                    *(ushort4*)&ga[swz(sp, sc + 0)]  = u0;
                    *(ushort4*)&ga[swz(sp, sc + 4)]  = u1;
                    *(ushort4*)&ga[swz(sp, sc + 8)]  = u2;
                    *(ushort4*)&ga[swz(sp, sc + 12)] = u3;
                }
                {
                    float4 v0 = *(const float4*)(wsrc + co0 + 0);
                    float4 v1 = *(const float4*)(wsrc + co0 + 4);
                    float4 v2 = *(const float4*)(wsrc + co0 + 8);
                    float4 v3 = *(const float4*)(wsrc + co0 + 12);
                    ushort4 u0 = {f2bf(v0.x), f2bf(v0.y), f2bf(v0.z), f2bf(v0.w)};
                    ushort4 u1 = {f2bf(v1.x), f2bf(v1.y), f2bf(v1.z), f2bf(v1.w)};
                    ushort4 u2 = {f2bf(v2.x), f2bf(v2.y), f2bf(v2.z), f2bf(v2.w)};
                    ushort4 u3 = {f2bf(v3.x), f2bf(v3.y), f2bf(v3.z), f2bf(v3.w)};
                    *(ushort4*)&wb[swz(sp, sc + 0)]  = u0;
                    *(ushort4*)&wb[swz(sp, sc + 4)]  = u1;
                    *(ushort4*)&wb[swz(sp, sc + 8)]  = u2;
                    *(ushort4*)&wb[swz(sp, sc + 12)] = u3;
                }
                __syncthreads();

                bf16x8 af[4], bf[4];
                #pragma unroll
                for (int mf = 0; mf < 4; ++mf) af[mf] = *(const bf16x8*)&ga[aoff[mf]];
                #pragma unroll
                for (int nf = 0; nf < 4; ++nf) bf[nf] = *(const bf16x8*)&wb[boff[nf]];
                #pragma unroll
                for (int mf = 0; mf < 4; ++mf)
                    #pragma unroll
                    for (int nf = 0; nf < 4; ++nf)
                        acc[mf][nf] = __builtin_amdgcn_mfma_f32_16x16x32_bf16(
                            af[mf], bf[nf], acc[mf][nf], 0, 0, 0);
            }
        }
    }

    #pragma unroll
    for (int mf = 0; mf < 4; ++mf) {
        #pragma unroll
        for (int rr = 0; rr < 4; ++rr) {
            const int P   = mtile * 128 + mbase + mf * 16 + q * 4 + rr;
            const int b   = P / NPIX;
            const int rem = P % NPIX;
            const int iy  = rem / WG, jx = rem % WG;
            const int y = 2 * iy + dy, x = 2 * jx + dx;
            float* orow = out + (size_t)((b * HIN + y) * WIN + x) * Cc
                              + ntile * 128 + nbase + r16;
            #pragma unroll
            for (int nf = 0; nf < 4; ++nf) orow[nf * 16] = acc[mf][nf][rr];
        }
    }
}

// ---------------------------------------------------------------------------
// grad_wt v3: per tap, C[ci][co] = sum_p X[p][ci] * G[p][co].
// Split-K = 64 (half batch per block): grid (4,9,64) = 2304 = 3 exact rounds.
// In-register transpose staging; incremental pixel decode (1 div/thread).
// ---------------------------------------------------------------------------
__global__ __launch_bounds__(256) void k_grad_wt(
    const float* __restrict__ g,      // [32,28,28,256]
    const float* __restrict__ inp,    // [32,56,56,256]
    float* __restrict__ gw)           // [3,3,256,256] pre-zeroed
{
    __shared__ unsigned short xa[128 * 64];   // [ci_local][pix64] swizzled
    __shared__ unsigned short xg[128 * 64];   // [co_local][pix64] swizzled

    const int t    = threadIdx.x;
    const int l    = t & 63;
    const int wave = t >> 6;
    const int mbase = (wave & 1) * 64;        // ci
    const int nbase = (wave >> 1) * 64;       // co
    const int q    = l >> 4;
    const int r16  = l & 15;

    const int tci = (blockIdx.x >> 1) * 128;
    const int tco = (blockIdx.x & 1) * 128;
    const int tap = blockIdx.y;
    const int ki = tap / 3, kj = tap % 3;
    const int bz   = blockIdx.z;              // 0..63
    const int b    = bz >> 1;
    const int pix0 = (bz & 1) * 392;
    const int pix_lim = pix0 + 392;

    // staging: thread owns pixels p0..p0+7 (within split), channels c4..c4+3
    const int pg = t >> 5;                    // 0..7
    const int p0 = pg * 8;
    const int c4 = (t & 31) * 4;              // 0..124

    f32x4 acc[4][4];
    #pragma unroll
    for (int a = 0; a < 4; ++a)
        #pragma unroll
        for (int c = 0; c < 4; ++c) acc[a][c] = (f32x4){0.f, 0.f, 0.f, 0.f};

    int aoff[2][4], boff[2][4];
    #pragma unroll
    for (int kk = 0; kk < 2; ++kk) {
        #pragma unroll
        for (int mf = 0; mf < 4; ++mf) {
            aoff[kk][mf] = swz64(mbase + mf * 16 + r16, kk * 32 + q * 8);
            boff[kk][mf] = swz64(nbase + mf * 16 + r16, kk * 32 + q * 8);
        }
    }

    const float* __restrict__ gb = g   + (size_t)b * NPIX * Cc;
    const float* __restrict__ ib = inp + (size_t)b * HIN * WIN * Cc;

    // incremental pixel decode: one division per thread
    int p_b = pix0 + p0;
    int i_b = p_b / WG;
    int j_b = p_b % WG;

    #pragma unroll 1
    for (int cc = 0; cc < 7; ++cc) {
        __syncthreads();
        // ---- stage X (in-register transpose, walked decode) ----
        {
            bf16x8 wx[4];
            int ii = i_b, jj = j_b;
            #pragma unroll
            for (int j = 0; j < 8; ++j) {
                const int r = ki + 2 * ii, s = kj + 2 * jj;
                const bool v = (p_b + j < pix_lim) && (r < HIN) && (s < WIN);
                float4 xv = make_float4(0.f, 0.f, 0.f, 0.f);
                if (v) xv = *(const float4*)(ib + (size_t)(r * WIN + s) * Cc + tci + c4);
                wx[0][j] = (short)f2bf(xv.x);
                wx[1][j] = (short)f2bf(xv.y);
                wx[2][j] = (short)f2bf(xv.z);
                wx[3][j] = (short)f2bf(xv.w);
                const int wsel = (jj == WG - 1);
                ii += wsel;
                jj = wsel ? 0 : jj + 1;
            }
            #pragma unroll
            for (int c = 0; c < 4; ++c)
                *(bf16x8*)&xa[swz64(c4 + c, p0)] = wx[c];
        }
        // ---- stage G (in-register transpose, linear addressing) ----
        {
            bf16x8 wgv[4];
            #pragma unroll
            for (int j = 0; j < 8; ++j) {
                const int p  = p_b + j;
                const bool v = (p < pix_lim);
                float4 gv = make_float4(0.f, 0.f, 0.f, 0.f);
                if (v) gv = *(const float4*)(gb + (size_t)p * Cc + tco + c4);
                wgv[0][j] = (short)f2bf(gv.x);
                wgv[1][j] = (short)f2bf(gv.y);
                wgv[2][j] = (short)f2bf(gv.z);
                wgv[3][j] = (short)f2bf(gv.w);
            }
            #pragma unroll
            for (int c = 0; c < 4; ++c)
                *(bf16x8*)&xg[swz64(c4 + c, p0)] = wgv[c];
        }
        __syncthreads();

        #pragma unroll
        for (int kk = 0; kk < 2; ++kk) {
            bf16x8 af[4], bfr[4];
            #pragma unroll
            for (int mf = 0; mf < 4; ++mf) af[mf]  = *(const bf16x8*)&xa[aoff[kk][mf]];
            #pragma unroll
            for (int nf = 0; nf < 4; ++nf) bfr[nf] = *(const bf16x8*)&xg[boff[kk][nf]];
            #pragma unroll
            for (int mf = 0; mf < 4; ++mf)
                #pragma unroll
                for (int nf = 0; nf < 4; ++nf)
                    acc[mf][nf] = __builtin_amdgcn_mfma_f32_16x16x32_bf16(
                        af[mf], bfr[nf], acc[mf][nf], 0, 0, 0);
        }

        // advance chunk base: p += 64 (64 = 2*28 + 8)
        p_b += 64;
        j_b += 8;
        i_b += 2;
        if (j_b >= WG) { j_b -= WG; i_b += 1; }
    }

    // epilogue: row = ci (4q+reg), col = co (r16)
    #pragma unroll
    for (int mf = 0; mf < 4; ++mf) {
        #pragma unroll
        for (int rr = 0; rr < 4; ++rr) {
            const int cirow = tci + mbase + mf * 16 + q * 4 + rr;
            float* dst = gw + (size_t)(tap * Cc + cirow) * Cc + tco + nbase + r16;
            #pragma unroll
            for (int nf = 0; nf < 4; ++nf) atomicAdd(dst + nf * 16, acc[mf][nf][rr]);
        }
    }
}

__global__ __launch_bounds__(256) void k_bias(
    const float* __restrict__ g, float* __restrict__ bias)
{
    const int t = threadIdx.x;
    const float* base = g + (size_t)blockIdx.x * 256 * Cc;
    float acc = 0.f;
    #pragma unroll 8
    for (int p = 0; p < 256; ++p) acc += base[(size_t)p * Cc + t];
    atomicAdd(bias + t, acc);
}

extern "C" void kernel_launch(void* const* d_in, const int* in_sizes, int n_in,
                              void* d_out, int out_size, void* d_ws, size_t ws_size,
                              hipStream_t stream) {
    const float* g   = (const float*)d_in[0];
    const float* inp = (const float*)d_in[1];
    const float* wt  = (const float*)d_in[2];
    float* out = (float*)d_out;

    const int nzero = GW_SIZE + 256;
    k_zero<<<(nzero + 255) / 256, 256, 0, stream>>>(out + GW_OFF, nzero);
    k_grad_in<<<dim3(196, 2, 4), 256, 0, stream>>>(g, wt, out);
    k_grad_wt<<<dim3(4, 9, 64), 256, 0, stream>>>(g, inp, out + GW_OFF);
    k_bias<<<98, 256, 0, stream>>>(g, out + BIAS_OFF);
}

// Round 5
// 227.872 us; speedup vs baseline: 1.3967x; 1.3967x over previous
//
#include <hip/hip_runtime.h>

#define Bn   32
#define HIN  56
#define WIN  56
#define Cc   256
#define HG   28
#define WG   28
#define NPIX (HG*WG)                    // 784

#define GIN_SIZE (Bn*HIN*WIN*Cc)        // 25690112
#define GW_SIZE  (9*Cc*Cc)              // 589824
#define GW_OFF   GIN_SIZE
#define BIAS_OFF (GW_OFF + GW_SIZE)

typedef short bf16x8 __attribute__((ext_vector_type(8)));
typedef float f32x4  __attribute__((ext_vector_type(4)));

// native bf16 convert (RNE) — compiler fuses pairs into v_cvt_pk_bf16_f32
__device__ __forceinline__ unsigned short f2bf(float f) {
    return __builtin_bit_cast(unsigned short, (__bf16)f);
}

// LDS-only barrier: waits ds ops, leaves global loads (vmcnt) IN FLIGHT.
// (__syncthreads would drain vmcnt(0) before s_barrier — the m97 stall.)
__device__ __forceinline__ void lds_barrier() {
    asm volatile("s_waitcnt lgkmcnt(0)" ::: "memory");
    __builtin_amdgcn_s_barrier();
    asm volatile("" ::: "memory");
}

// [row][32] bf16 tile, 16B-granule XOR swizzle (k_grad_in, proven R1)
__device__ __forceinline__ int swz(int row, int k) {
    int g2 = (k >> 3) ^ (row & 3) ^ ((row >> 2) & 3);
    return row * 32 + (g2 << 3) + (k & 7);
}

// [row][64] bf16 tile, 16B-granule XOR swizzle (k_grad_wt, proven R2)
__device__ __forceinline__ int swz64(int row, int k) {
    int gq = ((k >> 3) ^ (row & 7) ^ ((row >> 4) & 7)) & 7;
    return row * 64 + (gq << 3) + (k & 7);
}

__global__ __launch_bounds__(256) void k_zero(float* __restrict__ p, int n) {
    int i = blockIdx.x * 256 + threadIdx.x;
    if (i < n) p[i] = 0.f;
}

// ---------------------------------------------------------------------------
// grad_in: per parity class, D[pix][ci] = sum_{tap,co} G_shift[pix][co]*W[ci][co]
// R2 structure + reg-prefetch pipeline + lds_barrier (vmcnt never drained).
// grid = (196, 2, 4), 256 thr.
// ---------------------------------------------------------------------------
__global__ __launch_bounds__(256) void k_grad_in(
    const float* __restrict__ g,      // [32,28,28,256]
    const float* __restrict__ wt,     // [3,3,256,256]
    float* __restrict__ out)          // [32,56,56,256]
{
    __shared__ unsigned short ga[128 * 32];   // [pix_local][k=co32]
    __shared__ unsigned short wb[128 * 32];   // [ci_local][k=co32]

    const int t    = threadIdx.x;
    const int l    = t & 63;
    const int wave = t >> 6;
    const int mbase = (wave & 1) * 64;
    const int nbase = (wave >> 1) * 64;
    const int q    = l >> 4;
    const int r16  = l & 15;

    const int mtile = blockIdx.x;
    const int ntile = blockIdx.y;
    const int cls   = blockIdx.z;
    const int dy = cls >> 1, dx = cls & 1;

    const int sp = t >> 1;
    const int sc = (t & 1) * 16;
    const int P_s   = mtile * 128 + sp;
    const int b_s   = P_s / NPIX;
    const int rem_s = P_s % NPIX;
    const int iy_s  = rem_s / WG;
    const int jx_s  = rem_s % WG;
    const int sci   = ntile * 128 + sp;

    f32x4 acc[4][4];
    #pragma unroll
    for (int a = 0; a < 4; ++a)
        #pragma unroll
        for (int b = 0; b < 4; ++b) acc[a][b] = (f32x4){0.f, 0.f, 0.f, 0.f};

    int aoff[4], boff[4];
    #pragma unroll
    for (int mf = 0; mf < 4; ++mf) aoff[mf] = swz(mbase + mf * 16 + r16, q * 8);
    #pragma unroll
    for (int nf = 0; nf < 4; ++nf) boff[nf] = swz(nbase + nf * 16 + r16, q * 8);

    const int nky = dy ? 1 : 2;
    const int nkx = dx ? 1 : 2;

    for (int ty = 0; ty < nky; ++ty) {
        const int di   = dy ? 0 : (ty == 0 ? -1 : 0);
        const int krow = dy ? 1 : (ty == 0 ?  2 : 0);
        for (int tx = 0; tx < nkx; ++tx) {
            const int dj   = dx ? 0 : (tx == 0 ? -1 : 0);
            const int kcol = dx ? 1 : (tx == 0 ?  2 : 0);

            const int gi = iy_s + di, gj = jx_s + dj;
            const bool valid = (gi >= 0) && (gj >= 0);
            const float* __restrict__ gsrc = g + (size_t)((b_s * HG + gi) * WG + gj) * Cc + sc;
            const float* __restrict__ wsrc = wt + (size_t)((krow * 3 + kcol) * Cc + sci) * Cc + sc;

            float4 av[4], bv[4];
            // prologue load for this tap (co0 = 0)
            #pragma unroll
            for (int u = 0; u < 4; ++u) {
                av[u] = make_float4(0.f, 0.f, 0.f, 0.f);
                if (valid) av[u] = *(const float4*)(gsrc + u * 4);
                bv[u] = *(const float4*)(wsrc + u * 4);
            }

            #pragma unroll 1
            for (int co0 = 0; co0 < Cc; co0 += 32) {
                // convert current chunk from regs
                ushort4 ua[4], ub[4];
                #pragma unroll
                for (int u = 0; u < 4; ++u) {
                    ua[u] = (ushort4){f2bf(av[u].x), f2bf(av[u].y), f2bf(av[u].z), f2bf(av[u].w)};
                    ub[u] = (ushort4){f2bf(bv[u].x), f2bf(bv[u].y), f2bf(bv[u].z), f2bf(bv[u].w)};
                }
                // issue next chunk's loads NOW (in flight across barriers+MFMA)
                if (co0 + 32 < Cc) {
                    #pragma unroll
                    for (int u = 0; u < 4; ++u) {
                        float4 a2 = make_float4(0.f, 0.f, 0.f, 0.f);
                        if (valid) a2 = *(const float4*)(gsrc + co0 + 32 + u * 4);
                        float4 b2 = *(const float4*)(wsrc + co0 + 32 + u * 4);
                        av[u] = a2;
                        bv[u] = b2;
                    }
                }
                lds_barrier();   // prev MFMA done reading LDS
                #pragma unroll
                for (int u = 0; u < 4; ++u) {
                    *(ushort4*)&ga[swz(sp, sc + u * 4)] = ua[u];
                    *(ushort4*)&wb[swz(sp, sc + u * 4)] = ub[u];
                }
                lds_barrier();   // writes visible

                bf16x8 af[4], bf[4];
                #pragma unroll
                for (int mf = 0; mf < 4; ++mf) af[mf] = *(const bf16x8*)&ga[aoff[mf]];
                #pragma unroll
                for (int nf = 0; nf < 4; ++nf) bf[nf] = *(const bf16x8*)&wb[boff[nf]];
                #pragma unroll
                for (int mf = 0; mf < 4; ++mf)
                    #pragma unroll
                    for (int nf = 0; nf < 4; ++nf)
                        acc[mf][nf] = __builtin_amdgcn_mfma_f32_16x16x32_bf16(
                            af[mf], bf[nf], acc[mf][nf], 0, 0, 0);
            }
        }
    }

    #pragma unroll
    for (int mf = 0; mf < 4; ++mf) {
        #pragma unroll
        for (int rr = 0; rr < 4; ++rr) {
            const int P   = mtile * 128 + mbase + mf * 16 + q * 4 + rr;
            const int b   = P / NPIX;
            const int rem = P % NPIX;
            const int iy  = rem / WG, jx = rem % WG;
            const int y = 2 * iy + dy, x = 2 * jx + dx;
            float* orow = out + (size_t)((b * HIN + y) * WIN + x) * Cc
                              + ntile * 128 + nbase + r16;
            #pragma unroll
            for (int nf = 0; nf < 4; ++nf) orow[nf * 16] = acc[mf][nf][rr];
        }
    }
}

// ---------------------------------------------------------------------------
// grad_wt v4: R2 structure (split-K 32, grid (4,9,32), 13 chunks of K=64)
// + reg-prefetch pipeline + lds_barrier. Atomics into pre-zeroed gw.
// ---------------------------------------------------------------------------
__global__ __launch_bounds__(256) void k_grad_wt(
    const float* __restrict__ g,      // [32,28,28,256]
    const float* __restrict__ inp,    // [32,56,56,256]
    float* __restrict__ gw)           // [3,3,256,256] pre-zeroed
{
    __shared__ unsigned short xa[128 * 64];   // [ci_local][pix64] swizzled
    __shared__ unsigned short xg[128 * 64];   // [co_local][pix64] swizzled

    const int t    = threadIdx.x;
    const int l    = t & 63;
    const int wave = t >> 6;
    const int mbase = (wave & 1) * 64;        // ci
    const int nbase = (wave >> 1) * 64;       // co
    const int q    = l >> 4;
    const int r16  = l & 15;

    const int tci = (blockIdx.x >> 1) * 128;
    const int tco = (blockIdx.x & 1) * 128;
    const int tap = blockIdx.y;
    const int ki = tap / 3, kj = tap % 3;
    const int b  = blockIdx.z;

    // staging: thread owns pixels p0..p0+7, channels c4..c4+3
    const int pg = t >> 5;                    // 0..7
    const int p0 = pg * 8;
    const int c4 = (t & 31) * 4;              // 0..124

    f32x4 acc[4][4];
    #pragma unroll
    for (int a = 0; a < 4; ++a)
        #pragma unroll
        for (int c = 0; c < 4; ++c) acc[a][c] = (f32x4){0.f, 0.f, 0.f, 0.f};

    int aoff[2][4], boff[2][4];
    #pragma unroll
    for (int kk = 0; kk < 2; ++kk) {
        #pragma unroll
        for (int mf = 0; mf < 4; ++mf) {
            aoff[kk][mf] = swz64(mbase + mf * 16 + r16, kk * 32 + q * 8);
            boff[kk][mf] = swz64(nbase + mf * 16 + r16, kk * 32 + q * 8);
        }
    }

    const float* __restrict__ gb = g   + (size_t)b * NPIX * Cc;
    const float* __restrict__ ib = inp + (size_t)b * HIN * WIN * Cc;

    float4 xr[8], gr[8];

    auto load_chunk = [&](int cc) {
        #pragma unroll
        for (int j = 0; j < 8; ++j) {
            const int p  = cc * 64 + p0 + j;
            const int i  = p / WG, jw = p % WG;     // magic-mul div, independent
            const int r  = ki + 2 * i, s = kj + 2 * jw;
            const bool vx = (p < NPIX) && (r < HIN) && (s < WIN);
            const bool vg = (p < NPIX);
            float4 xv = make_float4(0.f, 0.f, 0.f, 0.f);
            float4 gv = make_float4(0.f, 0.f, 0.f, 0.f);
            if (vx) xv = *(const float4*)(ib + (size_t)(r * WIN + s) * Cc + tci + c4);
            if (vg) gv = *(const float4*)(gb + (size_t)p * Cc + tco + c4);
            xr[j] = xv;
            gr[j] = gv;
        }
    };

    load_chunk(0);

    #pragma unroll 1
    for (int cc = 0; cc < 13; ++cc) {
        // convert current chunk (waits this chunk's vmcnt only)
        bf16x8 wx[4], wg[4];
        #pragma unroll
        for (int j = 0; j < 8; ++j) {
            wx[0][j] = (short)f2bf(xr[j].x);
            wx[1][j] = (short)f2bf(xr[j].y);
            wx[2][j] = (short)f2bf(xr[j].z);
            wx[3][j] = (short)f2bf(xr[j].w);
            wg[0][j] = (short)f2bf(gr[j].x);
            wg[1][j] = (short)f2bf(gr[j].y);
            wg[2][j] = (short)f2bf(gr[j].z);
            wg[3][j] = (short)f2bf(gr[j].w);
        }
        // issue next chunk's loads NOW — in flight across barriers + MFMA
        if (cc + 1 < 13) load_chunk(cc + 1);

        lds_barrier();   // prev MFMA done reading LDS
        #pragma unroll
        for (int c = 0; c < 4; ++c) {
            *(bf16x8*)&xa[swz64(c4 + c, p0)] = wx[c];
            *(bf16x8*)&xg[swz64(c4 + c, p0)] = wg[c];
        }
        lds_barrier();   // writes visible

        #pragma unroll
        for (int kk = 0; kk < 2; ++kk) {
            bf16x8 af[4], bfr[4];
            #pragma unroll
            for (int mf = 0; mf < 4; ++mf) af[mf]  = *(const bf16x8*)&xa[aoff[kk][mf]];
            #pragma unroll
            for (int nf = 0; nf < 4; ++nf) bfr[nf] = *(const bf16x8*)&xg[boff[kk][nf]];
            #pragma unroll
            for (int mf = 0; mf < 4; ++mf)
                #pragma unroll
                for (int nf = 0; nf < 4; ++nf)
                    acc[mf][nf] = __builtin_amdgcn_mfma_f32_16x16x32_bf16(
                        af[mf], bfr[nf], acc[mf][nf], 0, 0, 0);
        }
    }

    // epilogue: row = ci (4q+reg), col = co (r16)
    #pragma unroll
    for (int mf = 0; mf < 4; ++mf) {
        #pragma unroll
        for (int rr = 0; rr < 4; ++rr) {
            const int cirow = tci + mbase + mf * 16 + q * 4 + rr;
            float* dst = gw + (size_t)(tap * Cc + cirow) * Cc + tco + nbase + r16;
            #pragma unroll
            for (int nf = 0; nf < 4; ++nf) atomicAdd(dst + nf * 16, acc[mf][nf][rr]);
        }
    }
}

__global__ __launch_bounds__(256) void k_bias(
    const float* __restrict__ g, float* __restrict__ bias)
{
    const int t = threadIdx.x;
    const float* base = g + (size_t)blockIdx.x * 256 * Cc;
    float acc = 0.f;
    #pragma unroll 8
    for (int p = 0; p < 256; ++p) acc += base[(size_t)p * Cc + t];
    atomicAdd(bias + t, acc);
}

extern "C" void kernel_launch(void* const* d_in, const int* in_sizes, int n_in,
                              void* d_out, int out_size, void* d_ws, size_t ws_size,
                              hipStream_t stream) {
    const float* g   = (const float*)d_in[0];
    const float* inp = (const float*)d_in[1];
    const float* wt  = (const float*)d_in[2];
    float* out = (float*)d_out;

    const int nzero = GW_SIZE + 256;
    k_zero<<<(nzero + 255) / 256, 256, 0, stream>>>(out + GW_OFF, nzero);
    k_grad_in<<<dim3(196, 2, 4), 256, 0, stream>>>(g, wt, out);
    k_grad_wt<<<dim3(4, 9, 32), 256, 0, stream>>>(g, inp, out + GW_OFF);
    k_bias<<<98, 256, 0, stream>>>(g, out + BIAS_OFF);
}